// Round 1
// baseline (3918.735 us; speedup 1.0000x reference)
//
#include <hip/hip_runtime.h>
#include <hip/hip_bf16.h>
#include <stdint.h>

// ---------------------------------------------------------------------------
// DeepLSTMDecoderLayer: x[16,512,1024], mem[16,512,1024]
//   c = MHA_src(x, mem) + MHA_tgt_causal(x, x)
//   h = LSTM(concat(x, c)) ;  out = relu(h@W1+b1)@W2+b2
// Strategy R1: bf16 MFMA GEMMs (128x128 tile), flash attention 64x64 tiles,
// LSTM = precomputed gx (f32) + 512 sequential fused step kernels.
// ws layout (bytes, MiB units), peak ~260.2 MiB:
//   0 xb | 16 memb | 32 wt[8]x2 | 48 wlx | 56 wlc | 64 whp | 72 w1t | 80 w2t
//   88 bq | 104 bk | 120 bv | 136 ao_s | 152 ao_t | 168 c32(32) | 216 cb
//   232 hall | 248 cst(64K) | 248+64K hzero(32K)
//   overlays: gx f32 @88..216 (after attention), ffn1 bf16 @88..152 (after lstm)
// ---------------------------------------------------------------------------

typedef unsigned short u16;
typedef unsigned int u32;
typedef __bf16 bf16x8 __attribute__((ext_vector_type(8)));
typedef float f32x4 __attribute__((ext_vector_type(4)));
typedef int int32x4 __attribute__((ext_vector_type(4)));

#define DEV static __device__ __forceinline__

DEV u16 f2bf(float x) {
  u32 u = __builtin_bit_cast(u32, x);
  u += 0x7FFF + ((u >> 16) & 1);   // round-to-nearest-even
  return (u16)(u >> 16);
}

DEV bf16x8 ldfrag(const void* p) {
  int32x4 v = *(const int32x4*)p;
  return __builtin_bit_cast(bf16x8, v);
}

DEV f32x4 mfma_bf16(bf16x8 a, bf16x8 b, f32x4 c) {
  return __builtin_amdgcn_mfma_f32_16x16x32_bf16(a, b, c, 0, 0, 0);
}

// ---------------- conversion kernels ----------------

__global__ __launch_bounds__(256) void cvt_bf16_kernel(u16* __restrict__ out,
                                                       const float* __restrict__ in,
                                                       int n4) {
  int i = blockIdx.x * 256 + threadIdx.x;
  if (i >= n4) return;
  float4 v = ((const float4*)in)[i];
  ushort4 s;
  s.x = f2bf(v.x); s.y = f2bf(v.y); s.z = f2bf(v.z); s.w = f2bf(v.w);
  ((ushort4*)out)[i] = s;
}

// out[n*K + k] = in[(k+koff)*N + n] * scale   (tiled transpose-convert)
// grid: (N/32, K/32), block 256
__global__ __launch_bounds__(256) void convt_kernel(u16* __restrict__ out,
                                                    const float* __restrict__ in,
                                                    int K, int N, int koff, float scale) {
  __shared__ float tile[32][33];
  const int tid = threadIdx.x;
  const int n0 = blockIdx.x * 32, k0 = blockIdx.y * 32;
  const int c = tid & 31, r = tid >> 5;  // r in 0..7
#pragma unroll
  for (int i = 0; i < 4; ++i)
    tile[r + i * 8][c] = in[(size_t)(k0 + r + i * 8 + koff) * N + n0 + c];
  __syncthreads();
#pragma unroll
  for (int i = 0; i < 4; ++i)
    out[(size_t)(n0 + r + i * 8) * K + k0 + c] = f2bf(tile[c][r + i * 8] * scale);
}

// Wh packed: out[p*1024 + k] = lstm_w[(k+2048)*4096 + (p&3)*1024 + (p>>2)]
__global__ __launch_bounds__(256) void convt_perm_kernel(u16* __restrict__ out,
                                                         const float* __restrict__ in) {
  int idx = blockIdx.x * 256 + threadIdx.x;  // 4096*1024 total
  int p = idx >> 10, k = idx & 1023;
  out[idx] = f2bf(in[(size_t)(k + 2048) * 4096 + (p & 3) * 1024 + (p >> 2)]);
}

// ---------------- generic GEMM: C[M,N] = A[M,K](bf16) @ Bt[N,K]^T ----------------
// 128x128 tile, BK=32, 4 waves (2x2 of 64x64), reg-staged LDS.
template <int OUTBF, int ACCUM, int RELU>
__global__ __launch_bounds__(256) void gemm_bt_kernel(
    const u16* __restrict__ A, const u16* __restrict__ Bt,
    const float* __restrict__ bias, float bscale,
    void* __restrict__ outp, const float* __restrict__ cacc,
    int M, int N, int K) {
  __shared__ u16 As[128 * 32];
  __shared__ u16 Bs[128 * 32];
  const int tid = threadIdx.x;
  const int wave = tid >> 6, lane = tid & 63;
  const int lr = lane & 15, lg = lane >> 4;
  const int m0 = blockIdx.y * 128, n0 = blockIdx.x * 128;
  const int wr = (wave >> 1) * 64, wc = (wave & 1) * 64;

  f32x4 acc[4][4] = {};

  const int sr = tid >> 1;              // staging row 0..127
  const int sch = (tid & 1) * 16;       // staging chunk (elements)
  const u16* gA = A + (size_t)(m0 + sr) * K + sch;
  const u16* gB = Bt + (size_t)(n0 + sr) * K + sch;

  for (int k0 = 0; k0 < K; k0 += 32) {
    int32x4 va0 = *(const int32x4*)(gA + k0);
    int32x4 va1 = *(const int32x4*)(gA + k0 + 8);
    int32x4 vb0 = *(const int32x4*)(gB + k0);
    int32x4 vb1 = *(const int32x4*)(gB + k0 + 8);
    __syncthreads();  // previous iteration's compute done
    *(int32x4*)&As[sr * 32 + sch] = va0;
    *(int32x4*)&As[sr * 32 + sch + 8] = va1;
    *(int32x4*)&Bs[sr * 32 + sch] = vb0;
    *(int32x4*)&Bs[sr * 32 + sch + 8] = vb1;
    __syncthreads();
    bf16x8 af[4], bfr[4];
    const u16* pa = As + (wr + lr) * 32 + lg * 8;
    const u16* pb = Bs + (wc + lr) * 32 + lg * 8;
#pragma unroll
    for (int i = 0; i < 4; ++i) af[i] = ldfrag(pa + i * 16 * 32);
#pragma unroll
    for (int j = 0; j < 4; ++j) bfr[j] = ldfrag(pb + j * 16 * 32);
#pragma unroll
    for (int i = 0; i < 4; ++i)
#pragma unroll
      for (int j = 0; j < 4; ++j)
        acc[i][j] = mfma_bf16(af[i], bfr[j], acc[i][j]);
  }

  const int col0 = n0 + wc + lr;
  const int row0 = m0 + wr + lg * 4;
#pragma unroll
  for (int i = 0; i < 4; ++i) {
#pragma unroll
    for (int j = 0; j < 4; ++j) {
      const int c = col0 + j * 16;
      const float bv = bias ? bias[c] * bscale : 0.f;
#pragma unroll
      for (int ii = 0; ii < 4; ++ii) {
        const int r = row0 + i * 16 + ii;
        float v = acc[i][j][ii] + bv;
        if (ACCUM) v += cacc[(size_t)r * N + c];
        if (RELU) v = fmaxf(v, 0.f);
        if (OUTBF) ((u16*)outp)[(size_t)r * N + c] = f2bf(v);
        else       ((float*)outp)[(size_t)r * N + c] = v;
      }
    }
  }
}

// ---------------- flash attention ----------------
// grid (T/64, NH, B), 256 thr. Q pre-scaled. CAUSAL=1: arithmetic causal mask.
template <int CAUSAL>
__global__ __launch_bounds__(256) void flash_kernel(
    const u16* __restrict__ Q, const u16* __restrict__ Kb, const u16* __restrict__ Vb,
    const float* __restrict__ sbias, u16* __restrict__ O) {
  __shared__ u16 Kl[64 * 72];
  __shared__ u16 Vt[64 * 72];
  __shared__ u16 Pl[64 * 72];
  const int tid = threadIdx.x, wave = tid >> 6, lane = tid & 63;
  const int lr = lane & 15, lg = lane >> 4;
  const int q0 = blockIdx.x * 64, hh = blockIdx.y, b = blockIdx.z;

  bf16x8 qf[2];
  {
    const u16* qp = Q + (size_t)(b * 512 + q0 + wave * 16 + lr) * 1024 + hh * 64 + lg * 8;
    qf[0] = ldfrag(qp);
    qf[1] = ldfrag(qp + 32);
  }
  f32x4 oacc[4] = {};
  float mrun[4], lsum[4];
#pragma unroll
  for (int ii = 0; ii < 4; ++ii) { mrun[ii] = -3e38f; lsum[ii] = 0.f; }

  const int ntiles = CAUSAL ? (q0 / 64 + 1) : 8;
  for (int ti = 0; ti < ntiles; ++ti) {
    const int s0 = ti * 64;
    {  // stage K and V^T
      const int r = tid >> 2, ch = (tid & 3) * 16;
      const u16* kp = Kb + (size_t)(b * 512 + s0 + r) * 1024 + hh * 64 + ch;
      const u16* vp = Vb + (size_t)(b * 512 + s0 + r) * 1024 + hh * 64 + ch;
      int32x4 k0v = *(const int32x4*)kp;
      int32x4 k1v = *(const int32x4*)(kp + 8);
      int32x4 v0v = *(const int32x4*)vp;
      int32x4 v1v = *(const int32x4*)(vp + 8);
      *(int32x4*)&Kl[r * 72 + ch] = k0v;
      *(int32x4*)&Kl[r * 72 + ch + 8] = k1v;
      const u16* v0p = (const u16*)&v0v;
      const u16* v1p = (const u16*)&v1v;
#pragma unroll
      for (int j = 0; j < 8; ++j) {
        Vt[(ch + j) * 72 + r] = v0p[j];
        Vt[(ch + 8 + j) * 72 + r] = v1p[j];
      }
    }
    __syncthreads();
    // S = Q K^T
    f32x4 sf[4] = {};
#pragma unroll
    for (int j = 0; j < 4; ++j)
#pragma unroll
      for (int ks = 0; ks < 2; ++ks) {
        bf16x8 kf = ldfrag(&Kl[(j * 16 + lr) * 72 + ks * 32 + lg * 8]);
        sf[j] = mfma_bf16(qf[ks], kf, sf[j]);
      }
    if (!CAUSAL) {
#pragma unroll
      for (int j = 0; j < 4; ++j) {
        const float bv = sbias[b * 512 + s0 + j * 16 + lr];
#pragma unroll
        for (int ii = 0; ii < 4; ++ii) sf[j][ii] += bv;
      }
    } else {
#pragma unroll
      for (int j = 0; j < 4; ++j) {
        const int s = s0 + j * 16 + lr;
#pragma unroll
        for (int ii = 0; ii < 4; ++ii) {
          const int q = q0 + wave * 16 + lg * 4 + ii;
          if (s > q) sf[j][ii] -= 1e9f;
        }
      }
    }
    // online softmax
    float sc[4], rs[4];
#pragma unroll
    for (int ii = 0; ii < 4; ++ii) {
      float m = fmaxf(fmaxf(sf[0][ii], sf[1][ii]), fmaxf(sf[2][ii], sf[3][ii]));
#pragma unroll
      for (int off = 1; off < 16; off <<= 1) m = fmaxf(m, __shfl_xor(m, off));
      const float mn = fmaxf(mrun[ii], m);
      sc[ii] = __expf(mrun[ii] - mn);
      mrun[ii] = mn;
      rs[ii] = 0.f;
    }
#pragma unroll
    for (int j = 0; j < 4; ++j)
#pragma unroll
      for (int ii = 0; ii < 4; ++ii) {
        const float p = __expf(sf[j][ii] - mrun[ii]);
        rs[ii] += p;
        Pl[(wave * 16 + lg * 4 + ii) * 72 + j * 16 + lr] = f2bf(p);
      }
#pragma unroll
    for (int ii = 0; ii < 4; ++ii) {
      float r = rs[ii];
#pragma unroll
      for (int off = 1; off < 16; off <<= 1) r += __shfl_xor(r, off);
      lsum[ii] = lsum[ii] * sc[ii] + r;
    }
#pragma unroll
    for (int df = 0; df < 4; ++df)
#pragma unroll
      for (int ii = 0; ii < 4; ++ii) oacc[df][ii] *= sc[ii];
    __syncthreads();
    // O += P V
    bf16x8 pf[2];
    pf[0] = ldfrag(&Pl[(wave * 16 + lr) * 72 + lg * 8]);
    pf[1] = ldfrag(&Pl[(wave * 16 + lr) * 72 + 32 + lg * 8]);
#pragma unroll
    for (int df = 0; df < 4; ++df)
#pragma unroll
      for (int ks = 0; ks < 2; ++ks) {
        bf16x8 vf = ldfrag(&Vt[(df * 16 + lr) * 72 + ks * 32 + lg * 8]);
        oacc[df] = mfma_bf16(pf[ks], vf, oacc[df]);
      }
    __syncthreads();
  }
#pragma unroll
  for (int df = 0; df < 4; ++df)
#pragma unroll
    for (int ii = 0; ii < 4; ++ii) {
      const float v = oacc[df][ii] / lsum[ii];
      O[(size_t)(b * 512 + q0 + wave * 16 + lg * 4 + ii) * 1024 + hh * 64 + df * 16 + lr] =
          f2bf(v);
    }
}

// ---------------- LSTM step ----------------
// grid 128 (8 units each), 256 thr. Whp: [p=u*4+g][k], packed.
// g = hprev @ Wh (MFMA, 4 waves split K) + gx[:,t,:] -> gates -> c,h
__global__ __launch_bounds__(256) void lstm_step_kernel(
    const u16* __restrict__ Whp, const u16* __restrict__ hprev, int hstride,
    const float* __restrict__ gx, float* __restrict__ cst,
    u16* __restrict__ hall, int t) {
  __shared__ float part[4 * 16 * 32];
  const int tid = threadIdx.x, wave = tid >> 6, lane = tid & 63;
  const int lr = lane & 15, lg = lane >> 4;
  const int c0 = blockIdx.x * 32;  // packed col base
  f32x4 acc[2] = {};
  const u16* hp = hprev + (size_t)lr * hstride + wave * 256 + lg * 8;
  const u16* wp = Whp + (size_t)(c0 + lr) * 1024 + wave * 256 + lg * 8;
#pragma unroll
  for (int kc = 0; kc < 8; ++kc) {
    bf16x8 af = ldfrag(hp + kc * 32);
    bf16x8 b0 = ldfrag(wp + kc * 32);
    bf16x8 b1 = ldfrag(wp + 16 * 1024 + kc * 32);
    acc[0] = mfma_bf16(af, b0, acc[0]);
    acc[1] = mfma_bf16(af, b1, acc[1]);
  }
#pragma unroll
  for (int f = 0; f < 2; ++f)
#pragma unroll
    for (int ii = 0; ii < 4; ++ii)
      part[(wave * 16 + lg * 4 + ii) * 32 + f * 16 + lr] = acc[f][ii];
  __syncthreads();
  if (tid < 128) {
    const int ul = tid >> 4, b = tid & 15;
    const int u = blockIdx.x * 8 + ul;
    float g4[4];
#pragma unroll
    for (int g = 0; g < 4; ++g) {
      const int pc = ul * 4 + g;
      float s = part[(0 * 16 + b) * 32 + pc] + part[(1 * 16 + b) * 32 + pc] +
                part[(2 * 16 + b) * 32 + pc] + part[(3 * 16 + b) * 32 + pc];
      s += gx[((size_t)b * 512 + t) * 4096 + g * 1024 + u];
      g4[g] = s;
    }
    const float ig = 1.f / (1.f + __expf(-g4[0]));
    const float jg = 1.f - 2.f / (__expf(2.f * g4[1]) + 1.f);
    const float fg = 1.f / (1.f + __expf(-g4[2]));
    const float og = 1.f / (1.f + __expf(-g4[3]));
    const float cn = fg * cst[b * 1024 + u] + ig * jg;
    const float hn = og * (1.f - 2.f / (__expf(2.f * cn) + 1.f));
    cst[b * 1024 + u] = cn;
    hall[((size_t)b * 512 + t) * 1024 + u] = f2bf(hn);
  }
}

// ---------------- host ----------------

extern "C" void kernel_launch(void* const* d_in, const int* in_sizes, int n_in,
                              void* d_out, int out_size, void* d_ws, size_t ws_size,
                              hipStream_t stream) {
  const float* x        = (const float*)d_in[0];
  const float* mem      = (const float*)d_in[1];
  const float* src_bias = (const float*)d_in[2];
  // d_in[3] = tgt_bias (causal, computed arithmetically)
  const float* w_src_q = (const float*)d_in[4];  const float* b_src_q = (const float*)d_in[5];
  const float* w_src_k = (const float*)d_in[6];  const float* b_src_k = (const float*)d_in[7];
  const float* w_src_v = (const float*)d_in[8];  const float* b_src_v = (const float*)d_in[9];
  const float* w_src_o = (const float*)d_in[10]; const float* b_src_o = (const float*)d_in[11];
  const float* w_tgt_q = (const float*)d_in[12]; const float* b_tgt_q = (const float*)d_in[13];
  const float* w_tgt_k = (const float*)d_in[14]; const float* b_tgt_k = (const float*)d_in[15];
  const float* w_tgt_v = (const float*)d_in[16]; const float* b_tgt_v = (const float*)d_in[17];
  const float* w_tgt_o = (const float*)d_in[18]; const float* b_tgt_o = (const float*)d_in[19];
  const float* lstm_w  = (const float*)d_in[20]; const float* lstm_b  = (const float*)d_in[21];
  const float* w1 = (const float*)d_in[22]; const float* b1f = (const float*)d_in[23];
  const float* w2 = (const float*)d_in[24]; const float* b2f = (const float*)d_in[25];

  char* ws = (char*)d_ws;
  const size_t MiB = 1024ull * 1024ull;
  u16* xb   = (u16*)(ws + 0);
  u16* memb = (u16*)(ws + 16 * MiB);
  u16* wt[8];
  for (int i = 0; i < 8; ++i) wt[i] = (u16*)(ws + 32 * MiB + (size_t)i * 2 * MiB);
  u16* wlx = (u16*)(ws + 48 * MiB);
  u16* wlc = (u16*)(ws + 56 * MiB);
  u16* whp = (u16*)(ws + 64 * MiB);
  u16* w1t = (u16*)(ws + 72 * MiB);
  u16* w2t = (u16*)(ws + 80 * MiB);
  u16* bq   = (u16*)(ws + 88 * MiB);
  u16* bk   = (u16*)(ws + 104 * MiB);
  u16* bv   = (u16*)(ws + 120 * MiB);
  u16* ao_s = (u16*)(ws + 136 * MiB);
  u16* ao_t = (u16*)(ws + 152 * MiB);
  float* c32 = (float*)(ws + 168 * MiB);
  float* gx  = (float*)(ws + 88 * MiB);    // overlay (after attention phase)
  u16* cb    = (u16*)(ws + 216 * MiB);
  u16* hall  = (u16*)(ws + 232 * MiB);
  float* cst = (float*)(ws + 248 * MiB);
  u16* hzero = (u16*)(ws + 248 * MiB + 65536);
  u16* ffn1  = (u16*)(ws + 88 * MiB);      // overlay (after lstm phase)

  // --- conversions ---
  cvt_bf16_kernel<<<8192, 256, 0, stream>>>(xb, x, 2097152);
  cvt_bf16_kernel<<<8192, 256, 0, stream>>>(memb, mem, 2097152);
  const dim3 g1k(32, 32);
  convt_kernel<<<g1k, 256, 0, stream>>>(wt[0], w_src_q, 1024, 1024, 0, 0.125f);
  convt_kernel<<<g1k, 256, 0, stream>>>(wt[1], w_src_k, 1024, 1024, 0, 1.f);
  convt_kernel<<<g1k, 256, 0, stream>>>(wt[2], w_src_v, 1024, 1024, 0, 1.f);
  convt_kernel<<<g1k, 256, 0, stream>>>(wt[3], w_src_o, 1024, 1024, 0, 1.f);
  convt_kernel<<<g1k, 256, 0, stream>>>(wt[4], w_tgt_q, 1024, 1024, 0, 0.125f);
  convt_kernel<<<g1k, 256, 0, stream>>>(wt[5], w_tgt_k, 1024, 1024, 0, 1.f);
  convt_kernel<<<g1k, 256, 0, stream>>>(wt[6], w_tgt_v, 1024, 1024, 0, 1.f);
  convt_kernel<<<g1k, 256, 0, stream>>>(wt[7], w_tgt_o, 1024, 1024, 0, 1.f);
  convt_kernel<<<dim3(128, 32), 256, 0, stream>>>(wlx, lstm_w, 1024, 4096, 0, 1.f);
  convt_kernel<<<dim3(128, 32), 256, 0, stream>>>(wlc, lstm_w, 1024, 4096, 1024, 1.f);
  convt_perm_kernel<<<16384, 256, 0, stream>>>(whp, lstm_w);
  convt_kernel<<<dim3(128, 32), 256, 0, stream>>>(w1t, w1, 1024, 4096, 0, 1.f);
  convt_kernel<<<dim3(32, 128), 256, 0, stream>>>(w2t, w2, 4096, 1024, 0, 1.f);

  hipMemsetAsync(cst, 0, 16 * 1024 * 4, stream);
  hipMemsetAsync(hzero, 0, 16 * 1024 * 2, stream);

  const dim3 gN1(8, 64);   // N=1024, M=8192
  const dim3 gN4(32, 64);  // N=4096, M=8192

  // --- src attention ---
  gemm_bt_kernel<1, 0, 0><<<gN1, 256, 0, stream>>>(xb,   wt[0], b_src_q, 0.125f, bq, nullptr, 8192, 1024, 1024);
  gemm_bt_kernel<1, 0, 0><<<gN1, 256, 0, stream>>>(memb, wt[1], b_src_k, 1.f,    bk, nullptr, 8192, 1024, 1024);
  gemm_bt_kernel<1, 0, 0><<<gN1, 256, 0, stream>>>(memb, wt[2], b_src_v, 1.f,    bv, nullptr, 8192, 1024, 1024);
  flash_kernel<0><<<dim3(8, 16, 16), 256, 0, stream>>>(bq, bk, bv, src_bias, ao_s);
  // --- tgt (causal self) attention ---
  gemm_bt_kernel<1, 0, 0><<<gN1, 256, 0, stream>>>(xb, wt[4], b_tgt_q, 0.125f, bq, nullptr, 8192, 1024, 1024);
  gemm_bt_kernel<1, 0, 0><<<gN1, 256, 0, stream>>>(xb, wt[5], b_tgt_k, 1.f,    bk, nullptr, 8192, 1024, 1024);
  gemm_bt_kernel<1, 0, 0><<<gN1, 256, 0, stream>>>(xb, wt[6], b_tgt_v, 1.f,    bv, nullptr, 8192, 1024, 1024);
  flash_kernel<1><<<dim3(8, 16, 16), 256, 0, stream>>>(bq, bk, bv, nullptr, ao_t);
  // --- c = ao_s@Wo_s + bo_s + ao_t@Wo_t + bo_t ---
  gemm_bt_kernel<0, 0, 0><<<gN1, 256, 0, stream>>>(ao_s, wt[3], b_src_o, 1.f, c32, nullptr, 8192, 1024, 1024);
  gemm_bt_kernel<1, 1, 0><<<gN1, 256, 0, stream>>>(ao_t, wt[7], b_tgt_o, 1.f, cb,  c32,     8192, 1024, 1024);
  // --- gx = x@Wlx + lstm_b + c@Wlc ---
  gemm_bt_kernel<0, 0, 0><<<gN4, 256, 0, stream>>>(xb, wlx, lstm_b, 1.f, gx, nullptr, 8192, 4096, 1024);
  gemm_bt_kernel<0, 1, 0><<<gN4, 256, 0, stream>>>(cb, wlc, nullptr, 1.f, gx, gx,     8192, 4096, 1024);
  // --- LSTM scan ---
  for (int t = 0; t < 512; ++t) {
    const u16* hp = (t == 0) ? hzero : (hall + (size_t)(t - 1) * 1024);
    const int hstride = (t == 0) ? 1024 : (512 * 1024);
    lstm_step_kernel<<<128, 256, 0, stream>>>(whp, hp, hstride, gx, cst, hall, t);
  }
  // --- FFN ---
  gemm_bt_kernel<1, 0, 1><<<gN4, 256, 0, stream>>>(hall, w1t, b1f, 1.f, ffn1, nullptr, 8192, 4096, 1024);
  gemm_bt_kernel<0, 0, 0><<<gN1, 256, 0, stream>>>(ffn1, w2t, b2f, 1.f, (float*)d_out, nullptr, 8192, 1024, 4096);
}